// Round 1
// baseline (1432.431 us; speedup 1.0000x reference)
//
#include <hip/hip_runtime.h>

#define D_K 768
#define M_ROWS 4096
#define V_COLS 50257

typedef __attribute__((ext_vector_type(8))) __bf16 bf16x8;
typedef __attribute__((ext_vector_type(4))) float f32x4;

__device__ __forceinline__ unsigned short f2bf(float f) {
    unsigned int u = __float_as_uint(f);
    unsigned int r = (u + 0x7fffu + ((u >> 16) & 1u)) >> 16;
    return (unsigned short)r;
}

#define GLOAD_LDS16(g, l)                                                     \
    __builtin_amdgcn_global_load_lds(                                         \
        (const __attribute__((address_space(1))) void*)(g),                   \
        (__attribute__((address_space(3))) void*)(l), 16, 0, 0)

// ---------------- Kernel 1: gather + RMSNorm -> bf16 A ----------------
__global__ __launch_bounds__(256) void gather_norm(
    const int* __restrict__ seq, const float* __restrict__ emb,
    const float* __restrict__ w, unsigned short* __restrict__ outA) {
    const int r = blockIdx.x;      // 0..4095
    const int t = threadIdx.x;     // 0..255
    const int idx = seq[r];
    const float* src = emb + (size_t)idx * D_K;
    float x0 = src[t], x1 = src[t + 256], x2 = src[t + 512];
    float ss = x0 * x0 + x1 * x1 + x2 * x2;
    #pragma unroll
    for (int o = 32; o; o >>= 1) ss += __shfl_down(ss, o, 64);
    __shared__ float red[4];
    if ((t & 63) == 0) red[t >> 6] = ss;
    __syncthreads();
    float tot = red[0] + red[1] + red[2] + red[3];
    float scale = rsqrtf(tot * (1.0f / (float)D_K) + 1e-5f);
    unsigned short* dst = outA + (size_t)r * D_K;
    dst[t]       = f2bf(x0 * scale * w[t]);
    dst[t + 256] = f2bf(x1 * scale * w[t + 256]);
    dst[t + 512] = f2bf(x2 * scale * w[t + 512]);
}

// ---------------- Kernel 2: fp32 -> bf16 convert of W ----------------
__global__ __launch_bounds__(256) void convert_w(
    const float* __restrict__ w, unsigned short* __restrict__ out, int n4) {
    int i = blockIdx.x * 256 + threadIdx.x;
    if (i < n4) {
        float4 v = ((const float4*)w)[i];
        ushort4 o;
        o.x = f2bf(v.x); o.y = f2bf(v.y); o.z = f2bf(v.z); o.w = f2bf(v.w);
        ((ushort4*)out)[i] = o;
    }
}

// ---------------- Kernel 3: C[M,V] = A[M,K] * W[V,K]^T (bf16 MFMA) ----------------
__global__ __launch_bounds__(256) void gemm_nt(
    const unsigned short* __restrict__ A, const unsigned short* __restrict__ Bw,
    float* __restrict__ C) {
    __shared__ unsigned short As[128 * 32];
    __shared__ unsigned short Bs[128 * 32];

    const int tid = threadIdx.x;
    const int lane = tid & 63;
    const int w = tid >> 6;          // wave 0..3
    const int n_tile = blockIdx.x;   // 0..392
    const int m_tile = blockIdx.y;   // 0..31

    // staging: each wave fills 2 chunks of 1KB (16 rows x 32 cols bf16) in A and B
    const int row_in = lane >> 2;          // 0..15
    const int col8 = (lane & 3) * 8;       // 0,8,16,24
    const int c0 = w * 2;

    const int a_row0 = m_tile * 128 + c0 * 16 + row_in;
    const int a_row1 = a_row0 + 16;
    int b_row0 = n_tile * 128 + c0 * 16 + row_in;
    int b_row1 = b_row0 + 16;
    b_row0 = min(b_row0, V_COLS - 1);
    b_row1 = min(b_row1, V_COLS - 1);

    const unsigned short* gA0 = A + (size_t)a_row0 * D_K + col8;
    const unsigned short* gA1 = A + (size_t)a_row1 * D_K + col8;
    const unsigned short* gB0 = Bw + (size_t)b_row0 * D_K + col8;
    const unsigned short* gB1 = Bw + (size_t)b_row1 * D_K + col8;

    unsigned short* lA0 = As + c0 * 512 + lane * 8;
    unsigned short* lA1 = As + (c0 + 1) * 512 + lane * 8;
    unsigned short* lB0 = Bs + c0 * 512 + lane * 8;
    unsigned short* lB1 = Bs + (c0 + 1) * 512 + lane * 8;

    const int wm = (w >> 1) * 64;
    const int wn = (w & 1) * 64;
    const int frag_r = lane & 15;
    const int frag_k = (lane >> 4) * 8;

    f32x4 acc[4][4];
    #pragma unroll
    for (int i = 0; i < 4; i++)
        #pragma unroll
        for (int j = 0; j < 4; j++) acc[i][j] = (f32x4){0.f, 0.f, 0.f, 0.f};

    for (int kt = 0; kt < D_K / 32; ++kt) {
        GLOAD_LDS16(gA0, lA0);
        GLOAD_LDS16(gA1, lA1);
        GLOAD_LDS16(gB0, lB0);
        GLOAD_LDS16(gB1, lB1);
        gA0 += 32; gA1 += 32; gB0 += 32; gB1 += 32;
        __syncthreads();

        bf16x8 a[4], b[4];
        #pragma unroll
        for (int mi = 0; mi < 4; mi++)
            a[mi] = *(const bf16x8*)&As[(wm + mi * 16 + frag_r) * 32 + frag_k];
        #pragma unroll
        for (int ni = 0; ni < 4; ni++)
            b[ni] = *(const bf16x8*)&Bs[(wn + ni * 16 + frag_r) * 32 + frag_k];

        #pragma unroll
        for (int mi = 0; mi < 4; mi++)
            #pragma unroll
            for (int ni = 0; ni < 4; ni++)
                acc[mi][ni] = __builtin_amdgcn_mfma_f32_16x16x32_bf16(
                    a[mi], b[ni], acc[mi][ni], 0, 0, 0);
        __syncthreads();
    }

    // epilogue: col = lane&15, row = (lane>>4)*4 + reg
    const int crow_base = m_tile * 128 + wm + (lane >> 4) * 4;
    const int ccol_base = n_tile * 128 + wn + (lane & 15);
    #pragma unroll
    for (int mi = 0; mi < 4; mi++) {
        #pragma unroll
        for (int j = 0; j < 4; j++) {
            const int row = crow_base + mi * 16 + j;
            float* Crow = C + (size_t)row * V_COLS;
            #pragma unroll
            for (int ni = 0; ni < 4; ni++) {
                const int col = ccol_base + ni * 16;
                if (col < V_COLS) Crow[col] = acc[mi][ni][j];
            }
        }
    }
}

extern "C" void kernel_launch(void* const* d_in, const int* in_sizes, int n_in,
                              void* d_out, int out_size, void* d_ws, size_t ws_size,
                              hipStream_t stream) {
    const int* seq = (const int*)d_in[0];           // [2,2048] int32
    const float* emb = (const float*)d_in[1];       // [50257,768] f32
    const float* norm_w = (const float*)d_in[2];    // [768] f32
    const float* out_emb = (const float*)d_in[3];   // [50257,768] f32
    float* out = (float*)d_out;                     // [4096,50257] f32

    unsigned short* A_bf = (unsigned short*)d_ws;                          // 4096*768*2 = 6291456 B
    unsigned short* W_bf = (unsigned short*)((char*)d_ws + 6291456);       // 50257*768*2 B

    gather_norm<<<M_ROWS, 256, 0, stream>>>(seq, emb, norm_w, A_bf);

    const int n4 = V_COLS * D_K / 4;
    convert_w<<<(n4 + 255) / 256, 256, 0, stream>>>(out_emb, W_bf, n4);

    dim3 grid((V_COLS + 127) / 128, M_ROWS / 128);
    gemm_nt<<<grid, 256, 0, stream>>>(A_bf, W_bf, out);
}